// Round 3
// baseline (103.721 us; speedup 1.0000x reference)
//
#include <hip/hip_runtime.h>
#include <math.h>

#define BT 32768   // B*T tokens
#define DD 1024    // feature dim
#define NN 512     // buffer slots
#define PP 1024    // partial-sum blocks

__device__ __forceinline__ float fast_gelu(float x) {
    // 0.5*x*(1+tanh(c*(x+0.044715 x^3))), tanh(u) = 1 - 2/(exp(2u)+1)
    float u = 0.7978845608028654f * (x + 0.044715f * x * x * x);
    float e = __expf(2.0f * u);
    float t = 1.0f - __fdividef(2.0f, e + 1.0f);
    return 0.5f * x * (1.0f + t);
}

// Pass 1a: per-column partial sums of gelu(x). part[PP][DD]
__global__ __launch_bounds__(256) void k_partial(const float4* __restrict__ x4,
                                                 float4* __restrict__ part) {
    int t = threadIdx.x;  // 0..255 -> cols 4t..4t+3
    float4 acc = make_float4(0.f, 0.f, 0.f, 0.f);
    for (int row = blockIdx.x; row < BT; row += PP) {
        float4 v = x4[row * (DD / 4) + t];
        acc.x += fast_gelu(v.x);
        acc.y += fast_gelu(v.y);
        acc.z += fast_gelu(v.z);
        acc.w += fast_gelu(v.w);
    }
    part[blockIdx.x * (DD / 4) + t] = acc;
}

// Pass 1b: reduce PP partial rows -> 16 rows. 64 blocks x 256 thr.
__global__ __launch_bounds__(256) void k_reduce1(const float* __restrict__ part,
                                                 float* __restrict__ part2) {
    int g = blockIdx.x * 256 + threadIdx.x;  // 0..16383
    int col = g & (DD - 1);
    int chunk = g >> 10;  // 0..15
    float s = 0.f;
    int r0 = chunk * (PP / 16);
    for (int r = r0; r < r0 + PP / 16; ++r) s += part[r * DD + col];
    part2[chunk * DD + col] = s;
}

// Pass 1c: final mean, norm, normalized mean. 1 block x 1024 thr.
__global__ __launch_bounds__(1024) void k_mean_norm(const float* __restrict__ part2,
                                                    float* __restrict__ m_mean,
                                                    float* __restrict__ m_n,
                                                    float* __restrict__ nm_out) {
    int c = threadIdx.x;
    float s = 0.f;
    for (int r = 0; r < 16; ++r) s += part2[r * DD + c];
    float m = s * (1.0f / 32768.0f);
    m_mean[c] = m;
    __shared__ float red[1024];
    red[c] = m * m;
    __syncthreads();
    for (int st = 512; st > 0; st >>= 1) {
        if (c < st) red[c] += red[c + st];
        __syncthreads();
    }
    float nm = sqrtf(red[0]);
    float denom = fmaxf(nm, 1e-12f);
    m_n[c] = m / denom;
    if (c == 0) nm_out[0] = nm;
}

// sims prep: dot[n] = buf[n].m_mean ; sq[n] = ||buf[n]||^2. 512 blocks x 256 thr.
__global__ __launch_bounds__(256) void k_sims(const float4* __restrict__ buf4,
                                              const float4* __restrict__ m4,
                                              float* __restrict__ dot,
                                              float* __restrict__ sq) {
    int n = blockIdx.x;
    int t = threadIdx.x;
    float4 b = buf4[n * (DD / 4) + t];
    float4 m = m4[t];
    float d = b.x * m.x + b.y * m.y + b.z * m.z + b.w * m.w;
    float q = b.x * b.x + b.y * b.y + b.z * b.z + b.w * b.w;
    __shared__ float rd[256], rq[256];
    rd[t] = d;
    rq[t] = q;
    __syncthreads();
    for (int st = 128; st > 0; st >>= 1) {
        if (t < st) { rd[t] += rd[t + st]; rq[t] += rq[t + st]; }
        __syncthreads();
    }
    if (t == 0) { dot[n] = rd[0]; sq[n] = rq[0]; }
}

// argmax (first-index tie-break), gate, fired, small state outputs. 1 block x 512 thr.
__global__ __launch_bounds__(512) void k_state(const float* __restrict__ dot,
                                               const float* __restrict__ sq,
                                               const float* __restrict__ nm_p,
                                               const float* __restrict__ depl,
                                               const int* __restrict__ hits,
                                               const int* __restrict__ mask,   // int32 on device
                                               const float* __restrict__ logk_p,
                                               const float* __restrict__ loglam_p,
                                               const int* __restrict__ ptr_p,
                                               float* __restrict__ out_depl,
                                               float* __restrict__ out_hits,
                                               float* __restrict__ out_mask,
                                               float* __restrict__ gate_p) {
    int n = threadIdx.x;
    float nm = fmaxf(nm_p[0], 1e-12f);
    float nb = fmaxf(sqrtf(sq[n]), 1e-12f);
    bool mk = mask[n] != 0;
    float sim = mk ? dot[n] / (nb * nm) : -1.0f;

    __shared__ float ssim[512];
    __shared__ int sidx[512];
    ssim[n] = sim;
    sidx[n] = n;
    __syncthreads();
    for (int st = 256; st > 0; st >>= 1) {
        if (n < st) {
            float s2 = ssim[n + st];
            int i2 = sidx[n + st];
            if (s2 > ssim[n] || (s2 == ssim[n] && i2 < sidx[n])) {
                ssim[n] = s2;
                sidx[n] = i2;
            }
        }
        __syncthreads();
    }

    __shared__ int s_near, s_fired;
    if (n == 0) {
        int nearest = sidx[0];
        float msim = ssim[0];
        float k_depl = fminf(fmaxf(expf(logk_p[0]), 0.1f), 5.0f);
        float lam = fminf(fmaxf(expf(loglam_p[0]), 0.1f), 3.0f);
        float g = expf(-k_depl * (1.0f - depl[nearest]) - lam * (float)hits[nearest]);
        s_near = nearest;
        s_fired = (msim > 0.85f) ? 1 : 0;
        gate_p[0] = g;
    }
    __syncthreads();

    int ptr = ptr_p[0];
    float nd = depl[n];
    int nh = hits[n];
    float nmsk = mk ? 1.0f : 0.0f;
    if (n == s_near && s_fired) { nd *= 0.5f; nh += 1; }
    if (n == ptr) { nd = 1.0f; nh = 0; nmsk = 1.0f; }
    out_depl[n] = nd;
    out_hits[n] = (float)nh;
    out_mask[n] = nmsk;
}

// Pass 2: out = gelu(x) * gate. grid-stride float4.
__global__ __launch_bounds__(256) void k_out(const float4* __restrict__ x4,
                                             float4* __restrict__ o4,
                                             const float* __restrict__ gate_p,
                                             int n4) {
    float g = gate_p[0];
    int stride = gridDim.x * blockDim.x;
    for (int i = blockIdx.x * blockDim.x + threadIdx.x; i < n4; i += stride) {
        float4 v = x4[i];
        float4 r;
        r.x = fast_gelu(v.x) * g;
        r.y = fast_gelu(v.y) * g;
        r.z = fast_gelu(v.z) * g;
        r.w = fast_gelu(v.w) * g;
        o4[i] = r;
    }
}

// new_buf = buf with row ptr = m_n. 512 blocks x 256 thr, one float4 each.
__global__ __launch_bounds__(256) void k_buf(const float4* __restrict__ buf4,
                                             const float4* __restrict__ mn4,
                                             const int* __restrict__ ptr_p,
                                             float4* __restrict__ out4) {
    int i = blockIdx.x * 256 + threadIdx.x;  // 0..131071
    int row = i >> 8;  // 256 float4 per row
    float4 v = (row == ptr_p[0]) ? mn4[i & 255] : buf4[i];
    out4[i] = v;
}

extern "C" void kernel_launch(void* const* d_in, const int* in_sizes, int n_in,
                              void* d_out, int out_size, void* d_ws, size_t ws_size,
                              hipStream_t stream) {
    const float* x = (const float*)d_in[0];
    const float* log_k = (const float*)d_in[1];
    const float* log_lambda = (const float*)d_in[2];
    const float* buf = (const float*)d_in[3];
    const float* depl = (const float*)d_in[4];
    const int* hits = (const int*)d_in[5];
    const int* mask = (const int*)d_in[6];   // bool pushed as int32 per harness convention
    const int* ptr = (const int*)d_in[7];

    float* out = (float*)d_out;
    float* out_buf = out + 33554432;          // N*D
    float* out_depl = out_buf + NN * DD;      // 512
    float* out_hits = out_depl + NN;          // 512
    float* out_mask = out_hits + NN;          // 512

    // small scratch in ws (< 80 KB)
    float* ws = (float*)d_ws;
    float* part2 = ws;               // 16*1024
    float* m_mean = ws + 16384;      // 1024
    float* m_n = ws + 17408;         // 1024
    float* nm = ws + 18432;          // 1
    float* gate = ws + 18433;        // 1
    float* dot = ws + 18440;         // 512
    float* sq = ws + 18952;          // 512

    // big partial-sum scratch lives in the output region (PP*DD floats = 4 MB),
    // fully consumed before k_out overwrites it.
    float* part = out;

    k_partial<<<dim3(PP), dim3(256), 0, stream>>>((const float4*)x, (float4*)part);
    k_reduce1<<<dim3(64), dim3(256), 0, stream>>>(part, part2);
    k_mean_norm<<<dim3(1), dim3(1024), 0, stream>>>(part2, m_mean, m_n, nm);
    k_sims<<<dim3(NN), dim3(256), 0, stream>>>((const float4*)buf, (const float4*)m_mean, dot, sq);
    k_state<<<dim3(1), dim3(512), 0, stream>>>(dot, sq, nm, depl, hits, mask,
                                               log_k, log_lambda, ptr,
                                               out_depl, out_hits, out_mask, gate);
    k_out<<<dim3(2048), dim3(256), 0, stream>>>((const float4*)x, (float4*)out, gate, 8388608);
    k_buf<<<dim3(512), dim3(256), 0, stream>>>((const float4*)buf, (const float4*)m_n, ptr,
                                               (float4*)out_buf);
}